// Round 1
// baseline (318.330 us; speedup 1.0000x reference)
//
#include <hip/hip_runtime.h>

#define NJ  55
#define BLK 256

__global__ __launch_bounds__(BLK) void lbs_kernel(
    const float* __restrict__ points,
    const float* __restrict__ weights,
    const float* __restrict__ se3,
    float* __restrict__ out,
    int n_verts)
{
    // 256 rows x 55 floats = 56320 B LDS (2 blocks/CU at 160 KB)
    __shared__ float s_w[BLK * NJ];

    const int tid = threadIdx.x;
    const int block_start = blockIdx.x * BLK;
    const int nv = min(BLK, n_verts - block_start);

    // Stage this block's contiguous weight slab into LDS, coalesced.
    const float* wbase = weights + (size_t)block_start * NJ;
    if (nv == BLK) {
        // base offset = blockIdx*256*55*4 bytes, divisible by 16 -> float4 ok
        const float4* src = (const float4*)wbase;
        float4* dst = (float4*)s_w;
        #pragma unroll 4
        for (int i = tid; i < (BLK * NJ) / 4; i += BLK) dst[i] = src[i];
    } else {
        const int total = nv * NJ;
        for (int i = tid; i < total; i += BLK) s_w[i] = wbase[i];
    }
    __syncthreads();

    const int n = block_start + tid;
    if (n >= n_verts) return;

    float A[12];
    #pragma unroll
    for (int e = 0; e < 12; ++e) A[e] = 0.f;

    const float* wr = &s_w[tid * NJ];     // stride 55 (odd) -> bank-conflict-free
    const float4* M = (const float4*)se3; // wave-uniform -> s_load_dwordx4

    #pragma unroll 5
    for (int j = 0; j < NJ; ++j) {
        const float w = wr[j];
        const float4 r0 = M[j * 4 + 0];
        const float4 r1 = M[j * 4 + 1];
        const float4 r2 = M[j * 4 + 2];   // row 3 of SE3 never needed
        A[0] += w * r0.x; A[1] += w * r0.y; A[2]  += w * r0.z; A[3]  += w * r0.w;
        A[4] += w * r1.x; A[5] += w * r1.y; A[6]  += w * r1.z; A[7]  += w * r1.w;
        A[8] += w * r2.x; A[9] += w * r2.y; A[10] += w * r2.z; A[11] += w * r2.w;
    }

    const float px = points[n * 3 + 0];
    const float py = points[n * 3 + 1];
    const float pz = points[n * 3 + 2];

    out[n * 3 + 0] = A[0] * px + A[1] * py + A[2]  * pz + A[3];
    out[n * 3 + 1] = A[4] * px + A[5] * py + A[6]  * pz + A[7];
    out[n * 3 + 2] = A[8] * px + A[9] * py + A[10] * pz + A[11];
}

extern "C" void kernel_launch(void* const* d_in, const int* in_sizes, int n_in,
                              void* d_out, int out_size, void* d_ws, size_t ws_size,
                              hipStream_t stream) {
    const float* points  = (const float*)d_in[0];
    const float* weights = (const float*)d_in[1];
    const float* se3     = (const float*)d_in[2];
    float* out = (float*)d_out;

    const int n_verts = in_sizes[0] / 3;  // points is (N,3)
    const int grid = (n_verts + BLK - 1) / BLK;
    lbs_kernel<<<grid, BLK, 0, stream>>>(points, weights, se3, out, n_verts);
}